// Round 6
// baseline (449.452 us; speedup 1.0000x reference)
//
#include <hip/hip_runtime.h>

#define NN 65536
#define NE 1048576
#define HID 80

typedef unsigned int u32;
typedef unsigned short u16;

__device__ __forceinline__ u16 f2bf(float f) {
  u32 u = __float_as_uint(f);
  u = (u + 0x7fffu + ((u >> 16) & 1u)) >> 16;  // RNE
  return (u16)u;
}
__device__ __forceinline__ float bfhi(u32 packed) {
  return __uint_as_float(packed & 0xffff0000u);
}
__device__ __forceinline__ float bflo(u32 packed) {
  return __uint_as_float(packed << 16);
}

// ---------------- input projection: h = x @ W_in + b_in (bf16 out) ----------------
__global__ __launch_bounds__(256) void k_in(const float* __restrict__ x,
    const float* __restrict__ W, const float* __restrict__ b,
    u16* __restrict__ h) {
  int idx = blockIdx.x * 256 + threadIdx.x;
  if (idx >= NN * HID) return;
  int n = idx / HID, c = idx % HID;
  const float* xr = x + n * 16;
  float acc = b[c];
#pragma unroll
  for (int i = 0; i < 16; i++) acc += xr[i] * W[i * HID + c];
  h[idx] = f2bf(acc);
}

// ---------------- CSR build ----------------
// batched x4: 4 independent atomic chains per thread
__global__ __launch_bounds__(256) void k_hist(const int* __restrict__ dst,
                                              int* __restrict__ counts) {
  int base = blockIdx.x * 1024 + threadIdx.x;
  int d0 = dst[base], d1 = dst[base + 256], d2 = dst[base + 512],
      d3 = dst[base + 768];
  atomicAdd(&counts[d0], 1);
  atomicAdd(&counts[d1], 1);
  atomicAdd(&counts[d2], 1);
  atomicAdd(&counts[d3], 1);
}

__global__ __launch_bounds__(256) void k_scan1(const int* __restrict__ counts,
    int* __restrict__ offsets, int* __restrict__ blocksum) {
  __shared__ int sc[256];
  int t = threadIdx.x;
  int base = blockIdx.x * 1024 + t * 4;
  int c0 = counts[base], c1 = counts[base + 1], c2 = counts[base + 2],
      c3 = counts[base + 3];
  int s = c0 + c1 + c2 + c3;
  sc[t] = s;
  __syncthreads();
  for (int d = 1; d < 256; d <<= 1) {
    int v = (t >= d) ? sc[t - d] : 0;
    __syncthreads();
    sc[t] += v;
    __syncthreads();
  }
  int excl = sc[t] - s;
  offsets[base] = excl;
  offsets[base + 1] = excl + c0;
  offsets[base + 2] = excl + c0 + c1;
  offsets[base + 3] = excl + c0 + c1 + c2;
  if (t == 255) blocksum[blockIdx.x] = sc[255];
}

__global__ __launch_bounds__(64) void k_scan2(int* __restrict__ blocksum) {
  int t = threadIdx.x;
  int v = blocksum[t];
  int incl = v;
#pragma unroll
  for (int d = 1; d < 64; d <<= 1) {
    int o = __shfl_up(incl, d, 64);
    if (t >= d) incl += o;
  }
  blocksum[t] = incl - v;
}

__global__ __launch_bounds__(256) void k_scan3(int* __restrict__ offsets,
    const int* __restrict__ blocksum, int* __restrict__ cursors) {
  int i = blockIdx.x * 256 + threadIdx.x;
  int v = offsets[i] + blocksum[i >> 10];
  offsets[i] = v;
  cursors[i] = v;
}

// 32 B record per edge: [as_float(src), c0, c1, c2][c3, pad, pad, pad]
// batched x4 for atomic/scatter pipelining
__global__ __launch_bounds__(256) void k_fill(const int* __restrict__ src,
    const int* __restrict__ dst, const float4* __restrict__ eattr,
    int* __restrict__ cursors, float4* __restrict__ erec) {
  int base = blockIdx.x * 1024 + threadIdx.x;
#pragma unroll
  for (int k = 0; k < 4; k++) {
    int idx = base + k * 256;
    int d = dst[idx];
    float4 ea = eattr[idx];
    int s = src[idx];
    int pos = atomicAdd(&cursors[d], 1);
    erec[2 * pos] = make_float4(__int_as_float(s), ea.x, ea.y, ea.z);
    erec[2 * pos + 1] = make_float4(ea.w, 0.f, 0.f, 0.f);
  }
}

// ---------------- gather/aggregate: R[n][j][comp] = sum coef_j * h[src] ----------------
// Quarter-wave per node, NO LDS, no barriers: accumulators in registers, R out
// to global as bf16. Lane c owns comps {4c..4c+3, 64+c}. Occupancy is VGPR-
// bound only -> launch_bounds(256,6). Edge loop batched x4 (16 gathers in
// flight per wave).
__global__ __launch_bounds__(256, 6) void k_gather(const u16* __restrict__ hb_in,
    u16* __restrict__ Rg,
    const int* __restrict__ offsets, const int* __restrict__ counts,
    const float* __restrict__ erec) {
  const int tid = threadIdx.x;
  const int q = tid >> 4;
  const int c = tid & 15;
  const int n = blockIdx.x * 16 + q;

  float R[4][5];
#pragma unroll
  for (int j = 0; j < 4; j++)
#pragma unroll
    for (int i = 0; i < 5; i++) R[j][i] = 0.f;

  int start = offsets[n];
  int deg = counts[n];

  int e = 0;
  for (; e + 4 <= deg; e += 4) {
    const float* b0 = erec + (size_t)(start + e) * 8;
    float4 r0 = *(const float4*)(b0);
    float4 r1 = *(const float4*)(b0 + 8);
    float4 r2 = *(const float4*)(b0 + 16);
    float4 r3 = *(const float4*)(b0 + 24);
    float w0 = b0[4], wv1 = b0[12], wv2 = b0[20], wv3 = b0[28];
    const u16* p0 = hb_in + (size_t)__float_as_int(r0.x) * HID;
    const u16* p1 = hb_in + (size_t)__float_as_int(r1.x) * HID;
    const u16* p2 = hb_in + (size_t)__float_as_int(r2.x) * HID;
    const u16* p3 = hb_in + (size_t)__float_as_int(r3.x) * HID;
    uint2 ka = *(const uint2*)(p0 + 4 * c);
    uint2 kb = *(const uint2*)(p1 + 4 * c);
    uint2 kc = *(const uint2*)(p2 + 4 * c);
    uint2 kd = *(const uint2*)(p3 + 4 * c);
    u16 ta = p0[64 + c], tb = p1[64 + c], tc = p2[64 + c], td = p3[64 + c];
    float A[5], B[5], C[5], D[5];
    A[0] = bflo(ka.x); A[1] = bfhi(ka.x); A[2] = bflo(ka.y); A[3] = bfhi(ka.y);
    A[4] = bflo((u32)ta);
    B[0] = bflo(kb.x); B[1] = bfhi(kb.x); B[2] = bflo(kb.y); B[3] = bfhi(kb.y);
    B[4] = bflo((u32)tb);
    C[0] = bflo(kc.x); C[1] = bfhi(kc.x); C[2] = bflo(kc.y); C[3] = bfhi(kc.y);
    C[4] = bflo((u32)tc);
    D[0] = bflo(kd.x); D[1] = bfhi(kd.x); D[2] = bflo(kd.y); D[3] = bfhi(kd.y);
    D[4] = bflo((u32)td);
#pragma unroll
    for (int i = 0; i < 5; i++) {
      R[0][i] += r0.y * A[i] + r1.y * B[i] + r2.y * C[i] + r3.y * D[i];
      R[1][i] += r0.z * A[i] + r1.z * B[i] + r2.z * C[i] + r3.z * D[i];
      R[2][i] += r0.w * A[i] + r1.w * B[i] + r2.w * C[i] + r3.w * D[i];
      R[3][i] += w0 * A[i] + wv1 * B[i] + wv2 * C[i] + wv3 * D[i];
    }
  }
  for (; e < deg; e++) {
    const float* b0 = erec + (size_t)(start + e) * 8;
    float4 r0 = *(const float4*)(b0);
    float w0 = b0[4];
    const u16* p0 = hb_in + (size_t)__float_as_int(r0.x) * HID;
    uint2 ka = *(const uint2*)(p0 + 4 * c);
    u16 ta = p0[64 + c];
    float A[5];
    A[0] = bflo(ka.x); A[1] = bfhi(ka.x); A[2] = bflo(ka.y); A[3] = bfhi(ka.y);
    A[4] = bflo((u32)ta);
#pragma unroll
    for (int i = 0; i < 5; i++) {
      R[0][i] += r0.y * A[i];
      R[1][i] += r0.z * A[i];
      R[2][i] += r0.w * A[i];
      R[3][i] += w0 * A[i];
    }
  }

  // store R bf16: row layout [n][j][80]; lane c covers 4c..4c+3 (one uint2)
  // and 64+c (one u16). Quarter's uint2 stores are 128 B contiguous.
  u32* Rg32 = (u32*)Rg;
  size_t b32 = (size_t)n * 160 + 2 * c;
  size_t b16 = (size_t)n * 320 + 64 + c;
#pragma unroll
  for (int j = 0; j < 4; j++) {
    u32 lo = (u32)f2bf(R[j][0]) | ((u32)f2bf(R[j][1]) << 16);
    u32 hi = (u32)f2bf(R[j][2]) | ((u32)f2bf(R[j][3]) << 16);
    *(uint2*)(Rg32 + b32 + j * 40) = make_uint2(lo, hi);
    Rg[b16 + j * 80] = f2bf(R[j][4]);
  }
}

// ---------------- post-matmul: h_out[n] = weights applied to R[n] ----------------
// 16 nodes/block. Stage R (streamed, coalesced) -> fp32 LDS, then quarter-wave
// per node computes the 80 outputs. Scalar-output columns c and c+16 fused
// into one pass over a (halves Rlds[0] reads and the w2 T-recompute).
__global__ __launch_bounds__(256) void k_post(const u16* __restrict__ Rg,
    u16* __restrict__ hb_out,
    const float* __restrict__ w1, const float* __restrict__ w2,
    const float* __restrict__ w3, const float* __restrict__ w4) {
  __shared__ float Rlds[16][4][81];
  __shared__ float w1s[1024], w2s[512], w3s[512], w4s[256];
  int tid = threadIdx.x;
  for (int i = tid; i < 1024; i += 256) w1s[i] = w1[i];
  for (int i = tid; i < 512; i += 256) {
    w2s[i] = w2[i];
    w3s[i] = w3[i];
  }
  if (tid < 256) w4s[tid] = w4[tid];

  // stage: 16 nodes * 4 rows * 80 comps = 2560 u32 pairs; u32 index == p
  const u32* Rg32 = (const u32*)Rg + (size_t)blockIdx.x * 16 * 160;
#pragma unroll
  for (int it = 0; it < 10; it++) {
    int p = it * 256 + tid;
    int cp = p % 40;
    int row = p / 40;  // nd*4 + j
    u32 v = Rg32[p];
    Rlds[row >> 2][row & 3][2 * cp] = bflo(v);
    Rlds[row >> 2][row & 3][2 * cp + 1] = bfhi(v);
  }
  __syncthreads();

  const int q = tid >> 4;
  const int c = tid & 15;
  const int n = blockIdx.x * 16 + q;

  // norm constants: 1/sqrt2 * path fan-in norm * 1/sqrt(DEG)
  const float C1 = 0.03125f;      // 1/(sqrt2*sqrt32*4)
  const float C2 = 0.025515518f;  // 1/(sqrt2*sqrt48*4)
  const float C3 = 0.03125f;      // 1/(sqrt2*sqrt32*4)
  const float C4 = 0.044194174f;  // 1/(sqrt2*sqrt16*4)

  u16* op = hb_out + (size_t)n * HID;

  // scalar outputs c and c+16, fused over a
  float s0 = 0.f, s1 = 0.f;
#pragma unroll
  for (int a = 0; a < 32; a++) {
    float rs = Rlds[q][0][a];
    s0 += rs * w1s[a * 32 + c];
    s1 += rs * w1s[a * 32 + c + 16];
  }
  float t0 = 0.f, t1 = 0.f;
#pragma unroll
  for (int a = 0; a < 16; a++) {
    float T = Rlds[q][1][32 + 3 * a] + Rlds[q][2][33 + 3 * a] +
              Rlds[q][3][34 + 3 * a];
    t0 += T * w2s[a * 32 + c];
    t1 += T * w2s[a * 32 + c + 16];
  }
  op[c] = f2bf(C1 * s0 + C2 * t0);
  op[c + 16] = f2bf(C1 * s1 + C2 * t1);

  // vector outputs: comps 32 + 16*i + c, i = 0..2
#pragma unroll
  for (int i = 0; i < 3; i++) {
    int c2 = 32 + 16 * i + c;
    int cv = (c2 - 32) / 3, k = (c2 - 32) % 3;
    float a3 = 0.f, a4 = 0.f;
#pragma unroll
    for (int a = 0; a < 32; a++) a3 += Rlds[q][k + 1][a] * w3s[a * 16 + cv];
#pragma unroll
    for (int a = 0; a < 16; a++)
      a4 += Rlds[q][0][32 + 3 * a + k] * w4s[a * 16 + cv];
    op[c2] = f2bf(C3 * a3 + C4 * a4);
  }
}

// ---------------- output projection: out = relu(h) @ W_out + b_out ----------------
__global__ __launch_bounds__(256) void k_out(const u16* __restrict__ h,
    const float* __restrict__ W, const float* __restrict__ b,
    float* __restrict__ out) {
  int idx = blockIdx.x * 256 + threadIdx.x;
  if (idx >= NN * 8) return;
  int n = idx >> 3, c = idx & 7;
  const u16* hr = h + (size_t)n * HID;
  float acc = b[c];
#pragma unroll 8
  for (int a = 0; a < HID; a++) {
    float v = bflo((u32)hr[a]);
    v = v > 0.f ? v : 0.f;
    acc += v * W[a * 8 + c];
  }
  out[idx] = acc;
}

extern "C" void kernel_launch(void* const* d_in, const int* in_sizes, int n_in,
                              void* d_out, int out_size, void* d_ws,
                              size_t ws_size, hipStream_t stream) {
  const float* x = (const float*)d_in[0];
  const int* ei = (const int*)d_in[1];
  const float* eattr = (const float*)d_in[2];
  const float* W_in = (const float*)d_in[3];
  const float* b_in = (const float*)d_in[4];
  const float* tp_w1 = (const float*)d_in[5];
  const float* tp_w2 = (const float*)d_in[6];
  const float* tp_w3 = (const float*)d_in[7];
  const float* tp_w4 = (const float*)d_in[8];
  const float* W_out = (const float*)d_in[9];
  const float* b_out = (const float*)d_in[10];
  float* out = (float*)d_out;

  char* ws = (char*)d_ws;
  size_t off = 0;
  auto alloc = [&](size_t bytes) {
    void* p = ws + off;
    off += (bytes + 255) & ~size_t(255);
    return p;
  };
  u16* h_a = (u16*)alloc((size_t)NN * HID * 2);
  u16* h_b = (u16*)alloc((size_t)NN * HID * 2);
  u16* Rg = (u16*)alloc((size_t)NN * 320 * 2);
  int* counts = (int*)alloc((size_t)NN * 4);
  int* offsets = (int*)alloc((size_t)NN * 4);
  int* cursors = (int*)alloc((size_t)NN * 4);
  int* blocksum = (int*)alloc(64 * 4);
  float4* erec = (float4*)alloc((size_t)NE * 32);

  const int* src = ei;
  const int* dst = ei + NE;

  hipMemsetAsync(counts, 0, (size_t)NN * 4, stream);
  k_in<<<(NN * HID + 255) / 256, 256, 0, stream>>>(x, W_in, b_in, h_a);
  k_hist<<<NE / 1024, 256, 0, stream>>>(dst, counts);
  k_scan1<<<64, 256, 0, stream>>>(counts, offsets, blocksum);
  k_scan2<<<1, 64, 0, stream>>>(blocksum);
  k_scan3<<<256, 256, 0, stream>>>(offsets, blocksum, cursors);
  k_fill<<<NE / 1024, 256, 0, stream>>>(src, dst, (const float4*)eattr,
                                        cursors, erec);

  u16* hin = h_a;
  u16* hout = h_b;
  for (int l = 0; l < 3; l++) {
    k_gather<<<NN / 16, 256, 0, stream>>>(hin, Rg, offsets, counts,
                                          (const float*)erec);
    k_post<<<NN / 16, 256, 0, stream>>>(Rg, hout, tp_w1 + l * 1024,
                                        tp_w2 + l * 512, tp_w3 + l * 512,
                                        tp_w4 + l * 256);
    u16* t = hin;
    hin = hout;
    hout = t;
  }
  k_out<<<(NN * 8 + 255) / 256, 256, 0, stream>>>(hin, W_out, b_out, out);
}

// Round 7
// 412.749 us; speedup vs baseline: 1.0889x; 1.0889x over previous
//
#include <hip/hip_runtime.h>

#define NN 65536
#define NE 1048576
#define HID 80

typedef unsigned int u32;
typedef unsigned short u16;

__device__ __forceinline__ u16 f2bf(float f) {
  u32 u = __float_as_uint(f);
  u = (u + 0x7fffu + ((u >> 16) & 1u)) >> 16;  // RNE
  return (u16)u;
}
__device__ __forceinline__ float bfhi(u32 packed) {
  return __uint_as_float(packed & 0xffff0000u);
}
__device__ __forceinline__ float bflo(u32 packed) {
  return __uint_as_float(packed << 16);
}

// ---------------- input projection: h = x @ W_in + b_in (bf16 out) ----------------
__global__ __launch_bounds__(256) void k_in(const float* __restrict__ x,
    const float* __restrict__ W, const float* __restrict__ b,
    u16* __restrict__ h) {
  int idx = blockIdx.x * 256 + threadIdx.x;
  if (idx >= NN * HID) return;
  int n = idx / HID, c = idx % HID;
  const float* xr = x + n * 16;
  float acc = b[c];
#pragma unroll
  for (int i = 0; i < 16; i++) acc += xr[i] * W[i * HID + c];
  h[idx] = f2bf(acc);
}

// ---------------- CSR build (padded segments) ----------------
__global__ __launch_bounds__(256) void k_hist(const int* __restrict__ dst,
                                              int* __restrict__ counts) {
  int base = blockIdx.x * 1024 + threadIdx.x;
  int d0 = dst[base], d1 = dst[base + 256], d2 = dst[base + 512],
      d3 = dst[base + 768];
  atomicAdd(&counts[d0], 1);
  atomicAdd(&counts[d1], 1);
  atomicAdd(&counts[d2], 1);
  atomicAdd(&counts[d3], 1);
}

// exclusive scan of counts PADDED up to multiples of 8 (branch-free gather loop)
__global__ __launch_bounds__(256) void k_scan1(const int* __restrict__ counts,
    int* __restrict__ offsets, int* __restrict__ blocksum) {
  __shared__ int sc[256];
  int t = threadIdx.x;
  int base = blockIdx.x * 1024 + t * 4;
  int p0 = (counts[base] + 7) & ~7;
  int p1 = (counts[base + 1] + 7) & ~7;
  int p2 = (counts[base + 2] + 7) & ~7;
  int p3 = (counts[base + 3] + 7) & ~7;
  int s = p0 + p1 + p2 + p3;
  sc[t] = s;
  __syncthreads();
  for (int d = 1; d < 256; d <<= 1) {
    int v = (t >= d) ? sc[t - d] : 0;
    __syncthreads();
    sc[t] += v;
    __syncthreads();
  }
  int excl = sc[t] - s;
  offsets[base] = excl;
  offsets[base + 1] = excl + p0;
  offsets[base + 2] = excl + p0 + p1;
  offsets[base + 3] = excl + p0 + p1 + p2;
  if (t == 255) blocksum[blockIdx.x] = sc[255];
}

__global__ __launch_bounds__(64) void k_scan2(int* __restrict__ blocksum) {
  int t = threadIdx.x;
  int v = blocksum[t];
  int incl = v;
#pragma unroll
  for (int d = 1; d < 64; d <<= 1) {
    int o = __shfl_up(incl, d, 64);
    if (t >= d) incl += o;
  }
  blocksum[t] = incl - v;
}

__global__ __launch_bounds__(256) void k_scan3(int* __restrict__ offsets,
    const int* __restrict__ blocksum, int* __restrict__ cursors) {
  int i = blockIdx.x * 256 + threadIdx.x;
  int v = offsets[i] + blocksum[i >> 10];
  offsets[i] = v;
  cursors[i] = v;
}

// 16 B record per edge: {src, bf16(c0,c1), bf16(c2,c3), 0} -> ONE 16 B store.
// Pad slots stay zero (memset): coef=0 contributes nothing in gather.
__global__ __launch_bounds__(256) void k_fill(const int* __restrict__ src,
    const int* __restrict__ dst, const float4* __restrict__ eattr,
    int* __restrict__ cursors, uint4* __restrict__ erec) {
  int base = blockIdx.x * 1024 + threadIdx.x;
#pragma unroll
  for (int k = 0; k < 4; k++) {
    int idx = base + k * 256;
    int d = dst[idx];
    float4 ea = eattr[idx];
    int s = src[idx];
    u32 c01 = (u32)f2bf(ea.x) | ((u32)f2bf(ea.y) << 16);
    u32 c23 = (u32)f2bf(ea.z) | ((u32)f2bf(ea.w) << 16);
    int pos = atomicAdd(&cursors[d], 1);
    erec[pos] = make_uint4((u32)s, c01, c23, 0u);
  }
}

// ---------------- per-layer message + aggregate + post-matmul (merged) ----------------
// 128 threads = 8 nodes/block, quarter-wave (16 lanes) per node.
// Edge loop: branch-free batch-8 over the padded segment -> 8 gathers in
// flight per quarter. Accumulators in registers; lane c owns comps
// {4c..4c+3, 64+c}. Transpose via wave-private LDS (no barrier: quarters only
// read their own slice). launch_bounds(128,4): 128-VGPR cap (round-2 lesson:
// watch WRITE_SIZE for spills).
__global__ __launch_bounds__(128, 4) void k_msg(const u16* __restrict__ hb_in,
    u16* __restrict__ hb_out,
    const float* __restrict__ w1, const float* __restrict__ w2,
    const float* __restrict__ w3, const float* __restrict__ w4,
    const int* __restrict__ offsets, const int* __restrict__ counts,
    const uint4* __restrict__ erec) {
  __shared__ float Rlds[8][4][81];
  __shared__ float w1s[1024], w2s[512], w3s[512], w4s[256];
  int tid = threadIdx.x;
  for (int i = tid; i < 1024; i += 128) w1s[i] = w1[i];
  for (int i = tid; i < 512; i += 128) {
    w2s[i] = w2[i];
    w3s[i] = w3[i];
  }
  for (int i = tid; i < 256; i += 128) w4s[i] = w4[i];
  __syncthreads();

  const int q = tid >> 4;
  const int c = tid & 15;
  const int n = blockIdx.x * 8 + q;

  float R[4][5];
#pragma unroll
  for (int j = 0; j < 4; j++)
#pragma unroll
    for (int i = 0; i < 5; i++) R[j][i] = 0.f;

  const int start = offsets[n];
  const int degp = (counts[n] + 7) & ~7;

  for (int e = 0; e < degp; e += 8) {
    uint4 rr[8];
    const int rbase = start + e;
#pragma unroll
    for (int k = 0; k < 8; k++) rr[k] = erec[rbase + k];
    uint2 kk[8];
    u32 tt[8];
#pragma unroll
    for (int k = 0; k < 8; k++) {
      const u16* p = hb_in + (size_t)rr[k].x * HID;
      kk[k] = *(const uint2*)(p + 4 * c);
      tt[k] = p[64 + c];
    }
#pragma unroll
    for (int k = 0; k < 8; k++) {
      float A0 = bflo(kk[k].x), A1 = bfhi(kk[k].x);
      float A2 = bflo(kk[k].y), A3 = bfhi(kk[k].y);
      float A4 = bflo(tt[k]);
      float f0 = bflo(rr[k].y), f1 = bfhi(rr[k].y);
      float f2 = bflo(rr[k].z), f3 = bfhi(rr[k].z);
      R[0][0] += f0 * A0; R[0][1] += f0 * A1; R[0][2] += f0 * A2;
      R[0][3] += f0 * A3; R[0][4] += f0 * A4;
      R[1][0] += f1 * A0; R[1][1] += f1 * A1; R[1][2] += f1 * A2;
      R[1][3] += f1 * A3; R[1][4] += f1 * A4;
      R[2][0] += f2 * A0; R[2][1] += f2 * A1; R[2][2] += f2 * A2;
      R[2][3] += f2 * A3; R[2][4] += f2 * A4;
      R[3][0] += f3 * A0; R[3][1] += f3 * A1; R[3][2] += f3 * A2;
      R[3][3] += f3 * A3; R[3][4] += f3 * A4;
    }
  }

  // transpose into component-indexed LDS (quarter-private slice, wave-sync)
#pragma unroll
  for (int j = 0; j < 4; j++) {
#pragma unroll
    for (int i = 0; i < 4; i++) Rlds[q][j][4 * c + i] = R[j][i];
    Rlds[q][j][64 + c] = R[j][4];
  }

  // norm constants: 1/sqrt2 * path fan-in norm * 1/sqrt(DEG)
  const float C1 = 0.03125f;      // 1/(sqrt2*sqrt32*4)
  const float C2 = 0.025515518f;  // 1/(sqrt2*sqrt48*4)
  const float C3 = 0.03125f;      // 1/(sqrt2*sqrt32*4)
  const float C4 = 0.044194174f;  // 1/(sqrt2*sqrt16*4)

  u16* op = hb_out + (size_t)n * HID;

  // scalar outputs c and c+16, fused over a
  float s0 = 0.f, s1 = 0.f;
#pragma unroll
  for (int a = 0; a < 32; a++) {
    float rs = Rlds[q][0][a];
    s0 += rs * w1s[a * 32 + c];
    s1 += rs * w1s[a * 32 + c + 16];
  }
  float t0 = 0.f, t1 = 0.f;
#pragma unroll
  for (int a = 0; a < 16; a++) {
    float T = Rlds[q][1][32 + 3 * a] + Rlds[q][2][33 + 3 * a] +
              Rlds[q][3][34 + 3 * a];
    t0 += T * w2s[a * 32 + c];
    t1 += T * w2s[a * 32 + c + 16];
  }
  op[c] = f2bf(C1 * s0 + C2 * t0);
  op[c + 16] = f2bf(C1 * s1 + C2 * t1);

  // vector outputs: comps 32 + 16*i + c
#pragma unroll
  for (int i = 0; i < 3; i++) {
    int c2 = 32 + 16 * i + c;
    int cv = (c2 - 32) / 3, k = (c2 - 32) % 3;
    float a3 = 0.f, a4 = 0.f;
#pragma unroll
    for (int a = 0; a < 32; a++) a3 += Rlds[q][k + 1][a] * w3s[a * 16 + cv];
#pragma unroll
    for (int a = 0; a < 16; a++)
      a4 += Rlds[q][0][32 + 3 * a + k] * w4s[a * 16 + cv];
    op[c2] = f2bf(C3 * a3 + C4 * a4);
  }
}

// ---------------- output projection: out = relu(h) @ W_out + b_out ----------------
__global__ __launch_bounds__(256) void k_out(const u16* __restrict__ h,
    const float* __restrict__ W, const float* __restrict__ b,
    float* __restrict__ out) {
  int idx = blockIdx.x * 256 + threadIdx.x;
  if (idx >= NN * 8) return;
  int n = idx >> 3, c = idx & 7;
  const u16* hr = h + (size_t)n * HID;
  float acc = b[c];
#pragma unroll 8
  for (int a = 0; a < HID; a++) {
    float v = bflo((u32)hr[a]);
    v = v > 0.f ? v : 0.f;
    acc += v * W[a * 8 + c];
  }
  out[idx] = acc;
}

extern "C" void kernel_launch(void* const* d_in, const int* in_sizes, int n_in,
                              void* d_out, int out_size, void* d_ws,
                              size_t ws_size, hipStream_t stream) {
  const float* x = (const float*)d_in[0];
  const int* ei = (const int*)d_in[1];
  const float* eattr = (const float*)d_in[2];
  const float* W_in = (const float*)d_in[3];
  const float* b_in = (const float*)d_in[4];
  const float* tp_w1 = (const float*)d_in[5];
  const float* tp_w2 = (const float*)d_in[6];
  const float* tp_w3 = (const float*)d_in[7];
  const float* tp_w4 = (const float*)d_in[8];
  const float* W_out = (const float*)d_in[9];
  const float* b_out = (const float*)d_in[10];
  float* out = (float*)d_out;

  char* ws = (char*)d_ws;
  size_t off = 0;
  auto alloc = [&](size_t bytes) {
    void* p = ws + off;
    off += (bytes + 255) & ~size_t(255);
    return p;
  };
  const size_t NEP = (size_t)NE + 8 * (size_t)NN;  // padded record bound
  u16* h_a = (u16*)alloc((size_t)NN * HID * 2);
  u16* h_b = (u16*)alloc((size_t)NN * HID * 2);
  int* counts = (int*)alloc((size_t)NN * 4);
  int* offsets = (int*)alloc((size_t)NN * 4);
  int* cursors = (int*)alloc((size_t)NN * 4);
  int* blocksum = (int*)alloc(64 * 4);
  uint4* erec = (uint4*)alloc(NEP * 16);

  const int* src = ei;
  const int* dst = ei + NE;

  hipMemsetAsync(counts, 0, (size_t)NN * 4, stream);
  hipMemsetAsync(erec, 0, NEP * 16, stream);
  k_in<<<(NN * HID + 255) / 256, 256, 0, stream>>>(x, W_in, b_in, h_a);
  k_hist<<<NE / 1024, 256, 0, stream>>>(dst, counts);
  k_scan1<<<64, 256, 0, stream>>>(counts, offsets, blocksum);
  k_scan2<<<1, 64, 0, stream>>>(blocksum);
  k_scan3<<<256, 256, 0, stream>>>(offsets, blocksum, cursors);
  k_fill<<<NE / 1024, 256, 0, stream>>>(src, dst, (const float4*)eattr,
                                        cursors, erec);

  u16* hin = h_a;
  u16* hout = h_b;
  for (int l = 0; l < 3; l++) {
    k_msg<<<NN / 8, 128, 0, stream>>>(hin, hout, tp_w1 + l * 1024,
                                      tp_w2 + l * 512, tp_w3 + l * 512,
                                      tp_w4 + l * 256, offsets, counts, erec);
    u16* t = hin;
    hin = hout;
    hout = t;
  }
  k_out<<<(NN * 8 + 255) / 256, 256, 0, stream>>>(hin, W_out, b_out, out);
}